// Round 11
// baseline (130.112 us; speedup 1.0000x reference)
//
#include <hip/hip_runtime.h>
#include <hip/hip_bf16.h>

// Fused windowed attention + FC projection for MI355X (gfx950).
// R11: R7 shell + two latency-chain attacks:
//  - softmax denominator via ones-row MFMA (S = mfma(ones,P,S)): the per-q
//    sum lands in-lane -> ZERO cross-lane ops in softmax (was 2 serial
//    shfl_xor LDS round-trips per (hh,ti)).
//  - both heads interleaved per ti (st0+st1, sm0+sm1, pv0+pv1): doubled
//    independent work at every latency point; VGPR budget 128 @ 4 blk/CU.

typedef __attribute__((ext_vector_type(8))) short bf8;   // 8 bf16 = 4 VGPRs
typedef __attribute__((ext_vector_type(4))) float f4;    // MFMA C/D

#define SCALE 0.17677669529663687f                 // 1/sqrt(32)
#define CC (SCALE * 1.4426950408889634f)           // SCALE * log2(e)

static __device__ __forceinline__ unsigned cvtpk(float lo, float hi) {
  unsigned r;
  asm("v_cvt_pk_bf16_f32 %0, %1, %2" : "=v"(r) : "v"(lo), "v"(hi));
  return r;
}
union FragU { unsigned u[4]; bf8 v; };

static __device__ __forceinline__ bf8 load_bf8_cvt(const float* __restrict__ p) {
  float4 a = *(const float4*)p;
  float4 b = *(const float4*)(p + 4);
  FragU f;
  f.u[0] = cvtpk(a.x, a.y);
  f.u[1] = cvtpk(a.z, a.w);
  f.u[2] = cvtpk(b.x, b.y);
  f.u[3] = cvtpk(b.z, b.w);
  return f.v;
}
static __device__ __forceinline__ bf8 load_bf8_cvt_scaled(const float* __restrict__ p) {
  float4 a = *(const float4*)p;
  float4 b = *(const float4*)(p + 4);
  FragU f;
  f.u[0] = cvtpk(a.x * CC, a.y * CC);
  f.u[1] = cvtpk(a.z * CC, a.w * CC);
  f.u[2] = cvtpk(b.x * CC, b.y * CC);
  f.u[3] = cvtpk(b.z * CC, b.w * CC);
  return f.v;
}

__global__ void wcvt(const float* __restrict__ W, unsigned short* __restrict__ Wb) {
  const int i = (blockIdx.x * 256 + threadIdx.x) * 4;
  float4 w = *(const float4*)(W + i);
  uint2 o;
  o.x = cvtpk(w.x, w.y);
  o.y = cvtpk(w.z, w.w);
  *(uint2*)(Wb + i) = o;
}

template <bool WB16>
__global__ __launch_bounds__(256, 4) void win_attn_fc(
    const float* __restrict__ q, const float* __restrict__ k,
    const float* __restrict__ v, const void* __restrict__ Wp,
    float* __restrict__ out) {
  // VT zone: 4 waves x 2 heads x [32 ch][72 tok] bf16 = 18432 us
  // inter [64 tok][280 ch-pad] = 17920 us aliased at 0 after barrier.
  __shared__ unsigned short smem[18432];
  const int tid  = threadIdx.x;
  const int wave = tid >> 6;
  const int lane = tid & 63;
  const int g    = lane >> 4;   // 0..3
  const int c16  = lane & 15;   // 0..15

  const int blk = blockIdx.x;
  const int b   = blk >> 8;          // 256 windows per batch
  const int wy  = (blk >> 4) & 15;
  const int wx  = blk & 15;
  const long tokbase = (long)b * 16384 + (long)(wy * 8) * 128 + wx * 8;

  unsigned short* VT0 = smem + wave * 4608;   // head 2w
  unsigned short* VT1 = VT0 + 2304;           // head 2w+1

  unsigned opk[2][2][4][2];  // [head][dt][ti][word]

  const int  srcA = c16 + ((g & 1) << 5);
  const bool hi   = (g >> 1) != 0;
  const int v_tcol = lane >> 3;
  const int v_cg   = lane & 7;

  // constant all-ones A fragment (bf16 1.0 pairs) for denominator MFMA
  FragU onesA;
  onesA.u[0] = 0x3F803F80u; onesA.u[1] = 0x3F803F80u;
  onesA.u[2] = 0x3F803F80u; onesA.u[3] = 0x3F803F80u;

  // ---- stage V^T for BOTH heads (coalesced, XOR-swizzled token blocks) ----
  #pragma unroll
  for (int hh = 0; hh < 2; ++hh) {
    const int h = wave * 2 + hh;
    unsigned short* VTh = hh ? VT1 : VT0;
    #pragma unroll
    for (int i = 0; i < 8; ++i) {
      const long r = tokbase + i * 128 + v_tcol;
      float4 vv = *(const float4*)(v + r * 256 + h * 32 + v_cg * 4);
      unsigned u01 = cvtpk(vv.x, vv.y);
      unsigned u23 = cvtpk(vv.z, vv.w);
      const int tswz = 8 * (i ^ v_cg) + v_tcol;
      VTh[(4*v_cg + 0) * 72 + tswz] = (unsigned short)u01;
      VTh[(4*v_cg + 1) * 72 + tswz] = (unsigned short)(u01 >> 16);
      VTh[(4*v_cg + 2) * 72 + tswz] = (unsigned short)u23;
      VTh[(4*v_cg + 3) * 72 + tswz] = (unsigned short)(u23 >> 16);
    }
  }

  // ---- all Q,K fragments for both heads up front (deep load pipeline) ----
  // A/B layout: row = l&15, k = 8*(l>>4)+j. Q pre-scaled by CC.
  bf8 qf[2][4], kf[2][4];
  #pragma unroll
  for (int hh = 0; hh < 2; ++hh) {
    const int h = wave * 2 + hh;
    #pragma unroll
    for (int t = 0; t < 4; ++t) {
      const int m = 16 * t + c16;
      const long r = tokbase + (m >> 3) * 128 + (m & 7);
      kf[hh][t] = load_bf8_cvt(k + r * 256 + h * 32 + g * 8);
      qf[hh][t] = load_bf8_cvt_scaled(q + r * 256 + h * 32 + g * 8);
    }
  }

  #pragma unroll
  for (int ti = 0; ti < 4; ++ti) {
    // ---- S^T tiles for BOTH heads (8 independent MFMAs) ----
    unsigned PW0[4][2], PW1[4][2];
    {
      f4 st0[4], st1[4];
      __builtin_amdgcn_s_setprio(1);
      #pragma unroll
      for (int tj = 0; tj < 4; ++tj) {
        f4 z = {0.f, 0.f, 0.f, 0.f};
        st0[tj] = __builtin_amdgcn_mfma_f32_16x16x32_bf16(kf[0][tj], qf[0][ti], z, 0, 0, 0);
      }
      #pragma unroll
      for (int tj = 0; tj < 4; ++tj) {
        f4 z = {0.f, 0.f, 0.f, 0.f};
        st1[tj] = __builtin_amdgcn_mfma_f32_16x16x32_bf16(kf[1][tj], qf[1][ti], z, 0, 0, 0);
      }
      __builtin_amdgcn_s_setprio(0);
      // ---- softmax both heads: pure VALU (no max-sub, no cross-lane) ----
      #pragma unroll
      for (int tj = 0; tj < 4; ++tj) {
        PW0[tj][0] = cvtpk(exp2f(st0[tj][0]), exp2f(st0[tj][1]));
        PW0[tj][1] = cvtpk(exp2f(st0[tj][2]), exp2f(st0[tj][3]));
        PW1[tj][0] = cvtpk(exp2f(st1[tj][0]), exp2f(st1[tj][1]));
        PW1[tj][1] = cvtpk(exp2f(st1[tj][2]), exp2f(st1[tj][3]));
      }
    }
    // ---- PV both heads; denominator via ones-row MFMA (in-lane sum) ----
    f4 a00 = {0.f,0.f,0.f,0.f}, a01 = {0.f,0.f,0.f,0.f}, s0 = {0.f,0.f,0.f,0.f};
    f4 a10 = {0.f,0.f,0.f,0.f}, a11 = {0.f,0.f,0.f,0.f}, s1 = {0.f,0.f,0.f,0.f};
    #pragma unroll
    for (int kt = 0; kt < 2; ++kt) {
      const int vo0 = (c16     ) * 72 + 8 * ((4*kt + g) ^ (c16 >> 2));
      const int vo1 = (16 + c16) * 72 + 8 * ((4*kt + g) ^ (4 + (c16 >> 2)));
      // head 0 P^T fragment
      {
        unsigned x0 = __shfl(PW0[2*kt  ][0], srcA);
        unsigned x1 = __shfl(PW0[2*kt  ][1], srcA);
        unsigned x2 = __shfl(PW0[2*kt  ][0], srcA + 16);
        unsigned x3 = __shfl(PW0[2*kt  ][1], srcA + 16);
        unsigned y0 = __shfl(PW0[2*kt+1][0], srcA);
        unsigned y1 = __shfl(PW0[2*kt+1][1], srcA);
        unsigned y2 = __shfl(PW0[2*kt+1][0], srcA + 16);
        unsigned y3 = __shfl(PW0[2*kt+1][1], srcA + 16);
        FragU pf;
        pf.u[0] = hi ? y0 : x0;
        pf.u[1] = hi ? y1 : x1;
        pf.u[2] = hi ? y2 : x2;
        pf.u[3] = hi ? y3 : x3;
        bf8 vf0 = *(const bf8*)(VT0 + vo0);
        bf8 vf1 = *(const bf8*)(VT0 + vo1);
        __builtin_amdgcn_s_setprio(1);
        a00 = __builtin_amdgcn_mfma_f32_16x16x32_bf16(vf0, pf.v, a00, 0, 0, 0);
        a01 = __builtin_amdgcn_mfma_f32_16x16x32_bf16(vf1, pf.v, a01, 0, 0, 0);
        s0  = __builtin_amdgcn_mfma_f32_16x16x32_bf16(onesA.v, pf.v, s0, 0, 0, 0);
        __builtin_amdgcn_s_setprio(0);
      }
      // head 1 P^T fragment
      {
        unsigned x0 = __shfl(PW1[2*kt  ][0], srcA);
        unsigned x1 = __shfl(PW1[2*kt  ][1], srcA);
        unsigned x2 = __shfl(PW1[2*kt  ][0], srcA + 16);
        unsigned x3 = __shfl(PW1[2*kt  ][1], srcA + 16);
        unsigned y0 = __shfl(PW1[2*kt+1][0], srcA);
        unsigned y1 = __shfl(PW1[2*kt+1][1], srcA);
        unsigned y2 = __shfl(PW1[2*kt+1][0], srcA + 16);
        unsigned y3 = __shfl(PW1[2*kt+1][1], srcA + 16);
        FragU pf;
        pf.u[0] = hi ? y0 : x0;
        pf.u[1] = hi ? y1 : x1;
        pf.u[2] = hi ? y2 : x2;
        pf.u[3] = hi ? y3 : x3;
        bf8 vf0 = *(const bf8*)(VT1 + vo0);
        bf8 vf1 = *(const bf8*)(VT1 + vo1);
        __builtin_amdgcn_s_setprio(1);
        a10 = __builtin_amdgcn_mfma_f32_16x16x32_bf16(vf0, pf.v, a10, 0, 0, 0);
        a11 = __builtin_amdgcn_mfma_f32_16x16x32_bf16(vf1, pf.v, a11, 0, 0, 0);
        s1  = __builtin_amdgcn_mfma_f32_16x16x32_bf16(onesA.v, pf.v, s1, 0, 0, 0);
        __builtin_amdgcn_s_setprio(0);
      }
    }
    // all rows of s equal the per-q-column denominator; rc is lane-local
    const float rc0 = __builtin_amdgcn_rcpf(s0[0]);
    const float rc1 = __builtin_amdgcn_rcpf(s1[0]);
    opk[0][0][ti][0] = cvtpk(a00[0] * rc0, a00[1] * rc0);
    opk[0][0][ti][1] = cvtpk(a00[2] * rc0, a00[3] * rc0);
    opk[0][1][ti][0] = cvtpk(a01[0] * rc0, a01[1] * rc0);
    opk[0][1][ti][1] = cvtpk(a01[2] * rc0, a01[3] * rc0);
    opk[1][0][ti][0] = cvtpk(a10[0] * rc1, a10[1] * rc1);
    opk[1][0][ti][1] = cvtpk(a10[2] * rc1, a10[3] * rc1);
    opk[1][1][ti][0] = cvtpk(a11[0] * rc1, a11[1] * rc1);
    opk[1][1][ti][1] = cvtpk(a11[2] * rc1, a11[3] * rc1);
  }

  // ---- assemble inter[64 tok][280 ch-pad] bf16 (aliases VT -> barrier) ----
  __syncthreads();
  unsigned short* inter = smem;
  #pragma unroll
  for (int hh = 0; hh < 2; ++hh)
    #pragma unroll
    for (int dt = 0; dt < 2; ++dt)
      #pragma unroll
      for (int ti = 0; ti < 4; ++ti) {
        const int addr = (16*ti + c16) * 280 + (wave*2 + hh) * 32 + 16*dt + 4*g;
        uint2 wv;
        wv.x = opk[hh][dt][ti][0];
        wv.y = opk[hh][dt][ti][1];
        *(uint2*)(inter + addr) = wv;   // 8B-aligned (all terms mult of 4 us)
      }
  __syncthreads();

  // ---- FC: out[tok][64w..64w+63] = inter[64][256] @ W^T ----
  f4 acc[4][4];
  #pragma unroll
  for (int mt = 0; mt < 4; ++mt)
    #pragma unroll
    for (int nt = 0; nt < 4; ++nt) {
      f4 z = {0.f, 0.f, 0.f, 0.f};
      acc[mt][nt] = z;
    }
  const float* Wf          = (const float*)Wp;
  const unsigned short* Wb = (const unsigned short*)Wp;
  #pragma unroll
  for (int ks = 0; ks < 8; ++ks) {
    bf8 af[4], wf[4];
    #pragma unroll
    for (int mt = 0; mt < 4; ++mt)
      af[mt] = *(const bf8*)(inter + (16*mt + c16) * 280 + 32*ks + 8*g);
    #pragma unroll
    for (int nt = 0; nt < 4; ++nt) {
      const long widx = (long)(64*wave + 16*nt + c16) * 256 + 32*ks + 8*g;
      if (WB16) wf[nt] = *(const bf8*)(Wb + widx);
      else      wf[nt] = load_bf8_cvt(Wf + widx);
    }
    __builtin_amdgcn_s_setprio(1);
    #pragma unroll
    for (int mt = 0; mt < 4; ++mt)
      #pragma unroll
      for (int nt = 0; nt < 4; ++nt)
        acc[mt][nt] = __builtin_amdgcn_mfma_f32_16x16x32_bf16(af[mt], wf[nt], acc[mt][nt], 0, 0, 0);
    __builtin_amdgcn_s_setprio(0);
  }

  // ---- epilogue: scatter back through window merge, fp32 stores ----
  #pragma unroll
  for (int mt = 0; mt < 4; ++mt) {
    #pragma unroll
    for (int r = 0; r < 4; ++r) {
      const int m = 16*mt + 4*g + r;
      const long row = tokbase + (m >> 3) * 128 + (m & 7);
      float* op = out + row * 256 + 64*wave + c16;
      #pragma unroll
      for (int nt = 0; nt < 4; ++nt)
        op[16*nt] = acc[mt][nt][r];
    }
  }
}

extern "C" void kernel_launch(void* const* d_in, const int* in_sizes, int n_in,
                              void* d_out, int out_size, void* d_ws, size_t ws_size,
                              hipStream_t stream) {
  const float* q = (const float*)d_in[0];
  const float* k = (const float*)d_in[1];
  const float* v = (const float*)d_in[2];
  const float* W = (const float*)d_in[3];
  float* out = (float*)d_out;
  const int B = in_sizes[0] / (16384 * 256);
  const size_t wbytes = 65536 * sizeof(unsigned short);
  if (ws_size >= wbytes) {
    wcvt<<<dim3(64), dim3(256), 0, stream>>>(W, (unsigned short*)d_ws);
    win_attn_fc<true><<<dim3(B * 256), dim3(256), 0, stream>>>(q, k, v, d_ws, out);
  } else {
    win_attn_fc<false><<<dim3(B * 256), dim3(256), 0, stream>>>(q, k, v, W, out);
  }
}